// Round 4
// baseline (796.973 us; speedup 1.0000x reference)
//
#include <hip/hip_runtime.h>
#include <math.h>

// SparseAttention B=2 H=16 S=2048 D=128, window half=102 (205 cols).
// out = ctx [B,H,S,D] ++ probs [B,H,S,S] (fp32).
// Round 4: overlap-focused. lgkm-only barriers (zero-fill stores drain in
// background), zero-fill moved to kernel end, Q direct-to-frag (no Qs LDS),
// bf16 Ps_t, 36.1 KB LDS -> 4 blocks/CU (__launch_bounds__(256,4)).

namespace {
constexpr int Sc = 2048, Dc = 128;
constexpr int HALFW = 102;
constexpr float SCALE = 0.08838834764831845f;   // 1/sqrt(128)
constexpr int TQ  = 32;    // q rows per block
constexpr int CT  = 256;   // padded window cols
constexpr int KST = 136;   // ushort stride for Ks rows
constexpr int VST = 132;   // float stride for Vsf rows
constexpr int PTS = 36;    // ushort stride for Ps_t per-k rows (32 + 4 pad)
// LDS layout (bytes); Ks overlays Ps_t+Vsf (disjoint phases)
constexpr int OFF_PST = 0;                       // Ps_t bf16 [256][36] = 18432
constexpr int OFF_VSF = 18432;                   // Vsf fp32 [32][132] = 16896
constexpr int SLAB    = 35328;                   // >= Ks (128*136*2 = 34816)
constexpr int OFF_RED = SLAB;
constexpr int LDS_TOTAL = SLAB + 512 + 128 + 128; // 36096 B -> 4 blocks/CU
}

typedef __bf16 bf16x8 __attribute__((ext_vector_type(8)));
typedef float  f32x16 __attribute__((ext_vector_type(16)));
typedef float  fx4    __attribute__((ext_vector_type(4)));
typedef unsigned short u16x8 __attribute__((ext_vector_type(8)));
typedef unsigned short u16x4 __attribute__((ext_vector_type(4)));

__device__ __forceinline__ unsigned short f2bf(float f) {
    unsigned u = __float_as_uint(f);
    u += 0x7fffu + ((u >> 16) & 1u);     // round-to-nearest-even
    return (unsigned short)(u >> 16);
}
__device__ __forceinline__ float bf2f(unsigned short h) {
    return __uint_as_float(((unsigned)h) << 16);
}
// LDS-only barrier: does NOT drain vmcnt, so global (zero-fill/probs/ctx)
// stores keep flowing. Safe: no global store is read in-kernel; LDS staging
// consumes loaded VGPRs (compiler inserts the per-use vmcnt waits).
__device__ __forceinline__ void bar_lds() {
    asm volatile("s_waitcnt lgkmcnt(0)\n\ts_barrier" ::: "memory");
}

__global__ __launch_bounds__(256, 4) void sparse_attn_mfma(
    const float* __restrict__ Q, const float* __restrict__ K,
    const float* __restrict__ V, float* __restrict__ ctx,
    float* __restrict__ probs)
{
    __shared__ __align__(16) unsigned char smem[LDS_TOTAL];
    unsigned short* Ks   = (unsigned short*)(smem);            // scores phase
    unsigned short* Ps_t = (unsigned short*)(smem + OFF_PST);  // PV phase
    float*          Vsf  = (float*)(smem + OFF_VSF);           // PV phase
    float (*red)[4]      = (float(*)[4])(smem + OFF_RED);
    float* rowM          = (float*)(smem + OFF_RED + 512);
    float* rowSinv       = (float*)(smem + OFF_RED + 512 + 128);

    const int tid  = threadIdx.x;
    const int lane = tid & 63;
    const int w    = tid >> 6;         // wave 0..3
    const int lo   = lane & 31;
    const int hi   = lane >> 5;

    // XCD-aware swizzle: adjacent q-tiles on the same XCD
    const int wid = (blockIdx.x & 7) * 256 + (blockIdx.x >> 3);
    const int bh  = wid >> 6;          // 0..31
    const int qt  = wid & 63;          // 0..63
    const int i0  = qt * TQ;
    const int js0 = max(0, i0 - HALFW);
    const int jend = min(js0 + CT, Sc);

    const size_t rowbase = (size_t)bh * Sc;
    float* probsBase = probs + (rowbase + i0) * (size_t)Sc;

    const float4* K4 = (const float4*)(K + rowbase * Dc);
    const float4* V4 = (const float4*)(V + rowbase * Dc);

    // ---------- Q directly into A-fragments (identical for all 4 waves) ----------
    // A[m=lo][k = dk*16 + hi*8 + j], j=0..7
    bf16x8 aq[8];
    {
        const float4* Q4 = (const float4*)(Q + (rowbase + i0) * Dc);
        #pragma unroll 2
        for (int dk = 0; dk < 8; ++dk) {
            float4 a = Q4[lo * 32 + dk * 4 + hi * 2];
            float4 b = Q4[lo * 32 + dk * 4 + hi * 2 + 1];
            u16x8 t;
            t[0] = f2bf(a.x); t[1] = f2bf(a.y); t[2] = f2bf(a.z); t[3] = f2bf(a.w);
            t[4] = f2bf(b.x); t[5] = f2bf(b.y); t[6] = f2bf(b.z); t[7] = f2bf(b.w);
            aq[dk] = __builtin_bit_cast(bf16x8, t);
        }
    }

    // ---------- Scores: 2 chunks of 128 K-rows; wave w does k-tile w per chunk ----------
    f32x16 accE[2];
    #pragma unroll
    for (int ch = 0; ch < 2; ++ch) {
        #pragma unroll 4
        for (int it = 0; it < 16; ++it) {
            int idx = tid + 256 * it;              // 0..4095
            int r = idx >> 5, d4 = idx & 31;
            int jn = js0 + ch * 128 + r;
            if (jn > Sc - 1) jn = Sc - 1;          // clamp; masked later
            float4 k4 = K4[(size_t)jn * 32 + d4];
            ushort4 b;
            b.x = f2bf(k4.x); b.y = f2bf(k4.y); b.z = f2bf(k4.z); b.w = f2bf(k4.w);
            *(ushort4*)&Ks[r * KST + d4 * 4] = b;
        }
        bar_lds();
        f32x16 acc;
        #pragma unroll
        for (int i = 0; i < 16; ++i) acc[i] = 0.0f;
        const unsigned short* krow = &Ks[(w * 32 + lo) * KST + hi * 8];
        #pragma unroll
        for (int dk = 0; dk < 8; ++dk) {
            bf16x8 b = *(const bf16x8*)(krow + dk * 16);
            acc = __builtin_amdgcn_mfma_f32_32x32x16_bf16(aq[dk], b, acc, 0, 0, 0);
        }
        accE[ch] = acc;
        bar_lds();   // before Ks region is overwritten
    }

    // ---------- Mask + scale, row-max ----------
    const int cg0 = js0 + w * 32 + lo;
    {
        float mred[16];
        #pragma unroll
        for (int i = 0; i < 16; ++i) {
            int rl = (i & 3) + 8 * (i >> 2) + 4 * hi;
            int rg = i0 + rl;
            float m = -3.0e38f;
            #pragma unroll
            for (int ch = 0; ch < 2; ++ch) {
                int cg = cg0 + ch * 128;
                bool valid = (cg < Sc) & (cg >= rg - HALFW) & (cg <= rg + HALFW);
                float sv = valid ? accE[ch][i] * SCALE : -3.0e38f;
                accE[ch][i] = sv;
                m = fmaxf(m, sv);
            }
            mred[i] = m;
        }
        #pragma unroll
        for (int mk = 1; mk < 32; mk <<= 1) {
            #pragma unroll
            for (int i = 0; i < 16; ++i)
                mred[i] = fmaxf(mred[i], __shfl_xor(mred[i], mk, 64));
        }
        if (lo == 0) {
            #pragma unroll
            for (int i = 0; i < 16; ++i) {
                int rl = (i & 3) + 8 * (i >> 2) + 4 * hi;
                red[rl][w] = mred[i];
            }
        }
    }
    bar_lds();
    if (tid < 128) {
        int rr = tid >> 2, sl = tid & 3;
        float v = red[rr][sl];
        v = fmaxf(v, __shfl_xor(v, 1, 64));
        v = fmaxf(v, __shfl_xor(v, 2, 64));
        if (sl == 0) rowM[rr] = v;
    }
    bar_lds();

    // ---------- exp + row-sum ----------
    {
        float sred[16];
        #pragma unroll
        for (int i = 0; i < 16; ++i) {
            int rl = (i & 3) + 8 * (i >> 2) + 4 * hi;
            float rm = rowM[rl];
            float e0 = __expf(accE[0][i] - rm);   // masked underflows to exact 0
            float e1 = __expf(accE[1][i] - rm);
            accE[0][i] = e0; accE[1][i] = e1;
            sred[i] = e0 + e1;
        }
        #pragma unroll
        for (int mk = 1; mk < 32; mk <<= 1) {
            #pragma unroll
            for (int i = 0; i < 16; ++i)
                sred[i] += __shfl_xor(sred[i], mk, 64);
        }
        if (lo == 0) {
            #pragma unroll
            for (int i = 0; i < 16; ++i) {
                int rl = (i & 3) + 8 * (i >> 2) + 4 * hi;
                red[rl][w] = sred[i];
            }
        }
    }
    bar_lds();
    if (tid < 128) {
        int rr = tid >> 2, sl = tid & 3;
        float v = red[rr][sl];
        v += __shfl_xor(v, 1, 64);
        v += __shfl_xor(v, 2, 64);
        if (sl == 0) rowSinv[rr] = 1.0f / v;
    }
    bar_lds();

    // ---------- probs: global in-window (NT, fp32) + transposed bf16 Ps_t ----------
    #pragma unroll
    for (int i = 0; i < 16; ++i) {
        int rl = (i & 3) + 8 * (i >> 2) + 4 * hi;
        float inv = rowSinv[rl];
        float* prow = probsBase + (size_t)rl * Sc;
        #pragma unroll
        for (int ch = 0; ch < 2; ++ch) {
            int cg = cg0 + ch * 128;
            float p = accE[ch][i] * inv;
            Ps_t[(cg - js0) * PTS + rl] = f2bf(p);  // (cg-js0) in [0,256)
            if (cg < Sc) __builtin_nontemporal_store(p, prow + cg);
        }
    }
    bar_lds();

    // ---------- PV: 8 chunks of 32 V-rows (fp32), 4 rows/lane, kp-split-4 ----------
    const int kp  = lane & 3;
    const int dgq = (lane >> 2) & 1;
    const int rg  = lane >> 3;
    fx4 o[4][4];
    #pragma unroll
    for (int c = 0; c < 4; ++c)
        #pragma unroll
        for (int j = 0; j < 4; ++j) o[c][j] = (fx4){0.f, 0.f, 0.f, 0.f};

    #pragma unroll 2
    for (int ch8 = 0; ch8 < 8; ++ch8) {
        #pragma unroll
        for (int it = 0; it < 4; ++it) {
            int idx = tid + 256 * it;             // 0..1023
            int r = idx >> 5, d4 = idx & 31;
            int jn = js0 + ch8 * 32 + r;
            if (jn > Sc - 1) jn = Sc - 1;         // p==0 there
            float4 v4g = V4[(size_t)jn * 32 + d4];
            *(float4*)&Vsf[r * VST + d4 * 4] = v4g;
        }
        bar_lds();
        const unsigned short* Pbase = &Ps_t[(ch8 * 32) * PTS + 4 * rg];
        const float* Vbase = &Vsf[w * 32 + dgq * 16];
        #pragma unroll 4
        for (int kk = 0; kk < 8; ++kk) {
            int k = 4 * kk + kp;
            u16x4 pb = *(const u16x4*)(Pbase + k * PTS);  // rows 4rg..4rg+3
            const float* vr = Vbase + k * VST;
            fx4 v0 = *(const fx4*)(vr);
            fx4 v1 = *(const fx4*)(vr + 4);
            fx4 v2 = *(const fx4*)(vr + 8);
            fx4 v3 = *(const fx4*)(vr + 12);
            #pragma unroll
            for (int c = 0; c < 4; ++c) {
                float pc = bf2f(pb[c]);
                o[c][0] += v0 * pc;
                o[c][1] += v1 * pc;
                o[c][2] += v2 * pc;
                o[c][3] += v3 * pc;
            }
        }
        bar_lds();
    }

    // reduce over kp (lane bits 0..1) via shfl, then store ctx
    #pragma unroll
    for (int c = 0; c < 4; ++c) {
        #pragma unroll
        for (int j = 0; j < 4; ++j) {
            fx4 t = o[c][j];
            #pragma unroll
            for (int comp = 0; comp < 4; ++comp) {
                float s = t[comp];
                s += __shfl_xor(s, 1, 64);
                s += __shfl_xor(s, 2, 64);
                t[comp] = s;
            }
            o[c][j] = t;
        }
    }
    if (kp == 0) {
        #pragma unroll
        for (int c = 0; c < 4; ++c) {
            float* crow = ctx + (rowbase + i0 + 4 * rg + c) * (size_t)Dc
                        + w * 32 + dgq * 16;
            #pragma unroll
            for (int j = 0; j < 4; ++j)
                __builtin_nontemporal_store(o[c][j], (fx4*)crow + j);
        }
    }

    // ---------- Zero-fill probs outside [js0, jend), at kernel end ----------
    {
        const int headN = js0 & 3;                 // 0 or 2
        const int tailN = (4 - (jend & 3)) & 3;    // 0 or 2
        const int hn = headN + tailN;
        if (hn == 4) {
            int r = tid >> 2, s = tid & 3;
            if (r < TQ) {
                int col = (s < headN) ? (js0 - headN + s) : (jend + s - headN);
                __builtin_nontemporal_store(0.0f, probsBase + (size_t)r * Sc + col);
            }
        } else if (hn == 2) {
            int r = tid >> 1, s = tid & 1;
            if (r < TQ) {
                int col = (s < headN) ? (js0 - headN + s) : (jend + s - headN);
                __builtin_nontemporal_store(0.0f, probsBase + (size_t)r * Sc + col);
            }
        }
        const int leftQ   = (js0 - headN) >> 2;
        const int rightQ0 = (jend + tailN) >> 2;
        const fx4 z4 = {0.f, 0.f, 0.f, 0.f};
        for (int r = 0; r < TQ; ++r) {
            fx4* p4 = (fx4*)(probsBase + (size_t)r * Sc);
            for (int c = tid; c < leftQ; c += 256)
                __builtin_nontemporal_store(z4, p4 + c);
            for (int c = rightQ0 + tid; c < Sc / 4; c += 256)
                __builtin_nontemporal_store(z4, p4 + c);
        }
    }
}

extern "C" void kernel_launch(void* const* d_in, const int* in_sizes, int n_in,
                              void* d_out, int out_size, void* d_ws, size_t ws_size,
                              hipStream_t stream) {
    const float* Q = (const float*)d_in[0];
    const float* K = (const float*)d_in[1];
    const float* V = (const float*)d_in[2];
    float* out   = (float*)d_out;
    float* ctx   = out;                                   // 2*16*2048*128
    float* probs = out + (size_t)2 * 16 * 2048 * 128;     // 2*16*2048*2048

    dim3 grid(2 * 16 * (Sc / TQ));   // 2048 blocks
    dim3 block(256);
    sparse_attn_mfma<<<grid, block, 0, stream>>>(Q, K, V, ctx, probs);
}